// Round 1
// baseline (400.449 us; speedup 1.0000x reference)
//
#include <hip/hip_runtime.h>

#define LOG2PI 1.8378770664093453f

// B=256, T=1024, D=256 (D assumed 256 = 64 lanes * float4).
// Grid: (4 t-chunks, B). Block: 256 threads = 4 waves.
// Each wave handles ~64 consecutive transitions for one batch; lanes span d
// via float4 (1 KiB coalesced per wave load). y_prev / ts_prev carried in
// registers so y is read from HBM exactly once.
__global__ __launch_bounds__(256) void ou_lp_kernel(
    const float* __restrict__ y,    // B*T*D
    const float* __restrict__ ts,   // T*D
    const float* __restrict__ mu,   // D
    const float* __restrict__ lk,   // D  log_kappa
    const float* __restrict__ ls,   // D  log_sigma
    float* __restrict__ out,        // B
    int B, int T, int D)
{
    const int b    = blockIdx.y;
    const int widx = threadIdx.x >> 6;        // wave index in block, 0..3
    const int lane = threadIdx.x & 63;
    const int d4   = lane * 4;                // this lane's d group
    const int NW   = gridDim.x * 4;           // total waves per batch (16)
    const int gw   = blockIdx.x * 4 + widx;   // global wave id for this batch
    const int NT   = T - 1;                   // transitions (1023)
    const int lo   = 1 + (NT * gw) / NW;      // first transition t (inclusive)
    const int hi   = 1 + (NT * (gw + 1)) / NW;// last transition t (exclusive)

    // ---- per-d constants (4 d's per lane) ----
    const float4 muv = *(const float4*)(mu + d4);
    const float4 lkv = *(const float4*)(lk + d4);
    const float4 lsv = *(const float4*)(ls + d4);

    float mur[4]   = {muv.x, muv.y, muv.z, muv.w};
    float lkr[4]   = {lkv.x, lkv.y, lkv.z, lkv.w};
    float lsr[4]   = {lsv.x, lsv.y, lsv.z, lsv.w};
    float kap[4], s2[4], inv2k[4];
    #pragma unroll
    for (int j = 0; j < 4; ++j) {
        // stable softplus: max(x,0) + log1p(exp(-|x|))
        float xk = lkr[j];
        float kappa = fmaxf(xk, 0.0f) + log1pf(__expf(-fabsf(xk)));
        kappa += 1e-6f;
        float xs = lsr[j];
        float sigma = fmaxf(xs, 0.0f) + log1pf(__expf(-fabsf(xs)));
        sigma += 1e-6f;
        kap[j]   = kappa;
        s2[j]    = sigma * sigma;
        inv2k[j] = 0.5f / kappa;
    }

    // ---- load t = lo-1 boundary row (y centered, ts) ----
    const size_t ybase = (size_t)b * T * D;
    float ypc[4], tsp[4], acc[4];
    {
        const float4 y0 = *(const float4*)(y  + ybase + (size_t)(lo - 1) * D + d4);
        const float4 t0 = *(const float4*)(ts + (size_t)(lo - 1) * D + d4);
        ypc[0] = y0.x - mur[0]; ypc[1] = y0.y - mur[1];
        ypc[2] = y0.z - mur[2]; ypc[3] = y0.w - mur[3];
        tsp[0] = t0.x; tsp[1] = t0.y; tsp[2] = t0.z; tsp[3] = t0.w;
    }
    acc[0] = acc[1] = acc[2] = acc[3] = 0.0f;

    // ---- lp0 term: only global wave 0 (its boundary row IS y[:,0,:]) ----
    if (gw == 0) {
        #pragma unroll
        for (int j = 0; j < 4; ++j) {
            float var0 = fmaxf(s2[j] * inv2k[j], 1e-10f);
            float yc   = ypc[j];
            acc[j] += __logf(var0) + LOG2PI + __fdividef(yc * yc, var0);
        }
    }

    // ---- main transition loop ----
    for (int t = lo; t < hi; ++t) {
        const float4 yt = *(const float4*)(y  + ybase + (size_t)t * D + d4);
        const float4 tt = *(const float4*)(ts + (size_t)t * D + d4);
        float ytr[4] = {yt.x, yt.y, yt.z, yt.w};
        float ttr[4] = {tt.x, tt.y, tt.z, tt.w};
        #pragma unroll
        for (int j = 0; j < 4; ++j) {
            float dt = fmaxf(ttr[j] - tsp[j], 1e-6f);
            float e  = __expf(-kap[j] * dt);          // Ad
            float q  = fmaxf(s2[j] * (1.0f - e * e) * inv2k[j], 1e-10f);
            float yc = ytr[j] - mur[j];
            float r  = yc - e * ypc[j];               // y_t - mean
            acc[j] += __logf(q) + LOG2PI + __fdividef(r * r, q);
            ypc[j] = yc;
            tsp[j] = ttr[j];
        }
    }

    // ---- reduce: lane -> wave -> block -> atomic ----
    float s = (acc[0] + acc[1]) + (acc[2] + acc[3]);
    #pragma unroll
    for (int off = 32; off > 0; off >>= 1)
        s += __shfl_down(s, off);

    __shared__ float wsum[4];
    if (lane == 0) wsum[widx] = s;
    __syncthreads();
    if (threadIdx.x == 0) {
        float tot = (wsum[0] + wsum[1]) + (wsum[2] + wsum[3]);
        atomicAdd(out + b, -0.5f * tot);
    }
}

extern "C" void kernel_launch(void* const* d_in, const int* in_sizes, int n_in,
                              void* d_out, int out_size, void* d_ws, size_t ws_size,
                              hipStream_t stream) {
    const float* y  = (const float*)d_in[0];
    const float* ts = (const float*)d_in[1];
    const float* mu = (const float*)d_in[2];
    const float* lk = (const float*)d_in[3];
    const float* ls = (const float*)d_in[4];
    float* out = (float*)d_out;

    const int D = in_sizes[2];               // 256
    const int T = in_sizes[1] / D;           // 1024
    const int B = in_sizes[0] / (T * D);     // 256

    // harness re-poisons d_out with 0xAA before every timed launch
    hipMemsetAsync(d_out, 0, (size_t)out_size * sizeof(float), stream);

    dim3 grid(4, B);
    dim3 block(256);
    ou_lp_kernel<<<grid, block, 0, stream>>>(y, ts, mu, lk, ls, out, B, T, D);
}

// Round 2
// 386.777 us; speedup vs baseline: 1.0353x; 1.0353x over previous
//
#include <hip/hip_runtime.h>

#define LOG2PI 1.8378770664093453f

// ---------------------------------------------------------------------------
// ws layout (bytes):
//   [0,4)                  float C      — batch-independent log-det constant
//   [256, 256+D*4)         float invvar0[D]
//   [4096, 4096+T*D*4)     float Ad[T*D]    (rows 1..T-1 valid)
//   [4096+T*D*4, +T*D*4)   float invq[T*D]  (rows 1..T-1 valid)
// ts_batch is (T,D) shared across batches, so Ad/q/log q are batch-independent.
// ---------------------------------------------------------------------------

__device__ __forceinline__ float block_reduce_add(float v, float* lds) {
    #pragma unroll
    for (int off = 32; off > 0; off >>= 1)
        v += __shfl_down(v, off);
    const int widx = threadIdx.x >> 6;
    const int lane = threadIdx.x & 63;
    if (lane == 0) lds[widx] = v;
    __syncthreads();
    float tot = 0.0f;
    if (threadIdx.x == 0) {
        const int nw = blockDim.x >> 6;
        for (int i = 0; i < nw; ++i) tot += lds[i];
    }
    return tot;  // valid on thread 0 only
}

// grid: T blocks of D threads. Block 0: lp0 constants. Block t>=1: transition t.
__global__ void ou_precompute_kernel(
    const float* __restrict__ ts, const float* __restrict__ lk,
    const float* __restrict__ ls,
    float* __restrict__ C, float* __restrict__ invvar0,
    float* __restrict__ Ad, float* __restrict__ invq,
    int T, int D)
{
    const int t = blockIdx.x;
    const int d = threadIdx.x;

    // softplus(x) = max(x,0) + log1p(exp(-|x|))
    float xk = lk[d];
    float kappa = fmaxf(xk, 0.0f) + log1pf(expf(-fabsf(xk))) + 1e-6f;
    float xs = ls[d];
    float sg = fmaxf(xs, 0.0f) + log1pf(expf(-fabsf(xs))) + 1e-6f;
    float s2 = sg * sg;
    float inv2k = 0.5f / kappa;

    float val;
    if (t == 0) {
        float var0 = fmaxf(s2 * inv2k, 1e-10f);
        invvar0[d] = 1.0f / var0;
        val = logf(var0) + LOG2PI;
    } else {
        float dt = fmaxf(ts[t * D + d] - ts[(t - 1) * D + d], 1e-6f);
        float e  = expf(-kappa * dt);
        float q  = fmaxf(s2 * (1.0f - e * e) * inv2k, 1e-10f);
        Ad[t * D + d]   = e;
        invq[t * D + d] = 1.0f / q;
        val = logf(q) + LOG2PI;
    }

    __shared__ float lds[8];
    float tot = block_reduce_add(val, lds);
    if (threadIdx.x == 0) atomicAdd(C, tot);
}

// ---------------------------------------------------------------------------
// Streaming kernel. grid (CH=8 chunks, B), block 256 = 4 waves.
// 2048 blocks -> 8 blocks/CU -> 32 waves/CU (full occupancy).
// Inner loop: pure FMA-class ops; y read once from HBM, Ad/invq from L2.
// ---------------------------------------------------------------------------
__global__ __launch_bounds__(256, 8) void ou_quad_kernel(
    const float* __restrict__ y,        // B*T*D
    const float* __restrict__ mu,       // D
    const float* __restrict__ C,        // scalar
    const float* __restrict__ invvar0,  // D
    const float* __restrict__ Ad,       // T*D
    const float* __restrict__ invq,     // T*D
    float* __restrict__ out,            // B
    int B, int T, int D)
{
    const int b    = blockIdx.y;
    const int widx = threadIdx.x >> 6;
    const int lane = threadIdx.x & 63;
    const int d4   = lane * 4;                 // D == 256 == 64 lanes * 4
    const int NW   = gridDim.x * 4;            // waves per batch (32)
    const int gw   = blockIdx.x * 4 + widx;
    const int NT   = T - 1;
    const int lo   = 1 + (NT * gw) / NW;
    const int hi   = 1 + (NT * (gw + 1)) / NW;

    const float4 muv = *(const float4*)(mu + d4);
    float mur[4] = {muv.x, muv.y, muv.z, muv.w};

    const size_t ybase = (size_t)b * T * D;
    float ypc[4], acc[4];
    {
        const float4 y0 = *(const float4*)(y + ybase + (size_t)(lo - 1) * D + d4);
        ypc[0] = y0.x - mur[0]; ypc[1] = y0.y - mur[1];
        ypc[2] = y0.z - mur[2]; ypc[3] = y0.w - mur[3];
    }
    acc[0] = acc[1] = acc[2] = acc[3] = 0.0f;

    // lp0 quadratic term (global wave 0 owns row 0)
    if (gw == 0) {
        const float4 iv = *(const float4*)(invvar0 + d4);
        float ivr[4] = {iv.x, iv.y, iv.z, iv.w};
        #pragma unroll
        for (int j = 0; j < 4; ++j) acc[j] += ypc[j] * ypc[j] * ivr[j];
    }

    const float* yp = y   + ybase + (size_t)lo * D + d4;
    const float* ap = Ad  + (size_t)lo * D + d4;
    const float* qp = invq + (size_t)lo * D + d4;

    // explicit depth-1 software pipeline: loads for t+1 issue before t's math
    float4 ycur = *(const float4*)yp;
    float4 acur = *(const float4*)ap;
    float4 qcur = *(const float4*)qp;
    for (int t = lo; t < hi; ++t) {
        float4 ynxt, anxt, qnxt;
        if (t + 1 < hi) {
            ynxt = *(const float4*)(yp + D);
            anxt = *(const float4*)(ap + D);
            qnxt = *(const float4*)(qp + D);
        }
        yp += D; ap += D; qp += D;

        float ytr[4] = {ycur.x, ycur.y, ycur.z, ycur.w};
        float adr[4] = {acur.x, acur.y, acur.z, acur.w};
        float iqr[4] = {qcur.x, qcur.y, qcur.z, qcur.w};
        #pragma unroll
        for (int j = 0; j < 4; ++j) {
            float yc = ytr[j] - mur[j];
            float r  = fmaf(-adr[j], ypc[j], yc);
            acc[j]   = fmaf(r * r, iqr[j], acc[j]);
            ypc[j]   = yc;
        }
        ycur = ynxt; acur = anxt; qcur = qnxt;
    }

    float s = (acc[0] + acc[1]) + (acc[2] + acc[3]);
    #pragma unroll
    for (int off = 32; off > 0; off >>= 1)
        s += __shfl_down(s, off);

    __shared__ float wsum[4];
    if (lane == 0) wsum[widx] = s;
    __syncthreads();
    if (threadIdx.x == 0) {
        float tot = (wsum[0] + wsum[1]) + (wsum[2] + wsum[3]);
        if (blockIdx.x == 0) tot += C[0];   // add log-det constant once per batch
        atomicAdd(out + b, -0.5f * tot);
    }
}

extern "C" void kernel_launch(void* const* d_in, const int* in_sizes, int n_in,
                              void* d_out, int out_size, void* d_ws, size_t ws_size,
                              hipStream_t stream) {
    const float* y  = (const float*)d_in[0];
    const float* ts = (const float*)d_in[1];
    const float* mu = (const float*)d_in[2];
    const float* lk = (const float*)d_in[3];
    const float* ls = (const float*)d_in[4];
    float* out = (float*)d_out;

    const int D = in_sizes[2];               // 256
    const int T = in_sizes[1] / D;           // 1024
    const int B = in_sizes[0] / (T * D);     // 256

    char* ws = (char*)d_ws;
    float* C       = (float*)(ws);
    float* invvar0 = (float*)(ws + 256);
    float* Ad      = (float*)(ws + 4096);
    float* invq    = (float*)(ws + 4096 + (size_t)T * D * sizeof(float));

    hipMemsetAsync(d_out, 0, (size_t)out_size * sizeof(float), stream);
    hipMemsetAsync(C, 0, sizeof(float), stream);

    ou_precompute_kernel<<<dim3(T), dim3(D), 0, stream>>>(
        ts, lk, ls, C, invvar0, Ad, invq, T, D);

    dim3 grid(8, B);
    ou_quad_kernel<<<grid, dim3(256), 0, stream>>>(
        y, mu, C, invvar0, Ad, invq, out, B, T, D);
}

// Round 3
// 348.457 us; speedup vs baseline: 1.1492x; 1.1100x over previous
//
#include <hip/hip_runtime.h>

#define LOG2PI 1.8378770664093453f

typedef float f4 __attribute__((ext_vector_type(4)));

// ---------------------------------------------------------------------------
// Fused OU log-prob kernel. B=256, T=1024, D=256 (64 lanes * float4).
// Grid (8 t-chunks, B/2); block 256 = 4 waves; 1024 blocks = 4 blocks/CU =
// 16 waves/CU at the 128-VGPR cap (launch_bounds(256,4) -> 4 waves/EU).
// Each wave owns ~32 consecutive transitions for a PAIR of batches:
//   - ts row loaded once (L2-resident, 1 MiB), dt/Ad/q/log q computed once
//     per pair (exp+rcp+log ~= 7 us chip-wide, hidden under the y stream)
//   - y rows for both batches streamed non-temporally (read exactly once)
// y_prev / ts_prev carried in registers. atomicAdd(out) once per block/batch.
// ---------------------------------------------------------------------------
__global__ __launch_bounds__(256, 4) void ou_fused_kernel(
    const float* __restrict__ y,    // B*T*D
    const float* __restrict__ ts,   // T*D
    const float* __restrict__ mu,   // D
    const float* __restrict__ lk,   // D
    const float* __restrict__ ls,   // D
    float* __restrict__ out,        // B
    int B, int T, int D)
{
    const int b0   = blockIdx.y * 2;
    const int b1   = b0 + 1;
    const int widx = threadIdx.x >> 6;
    const int lane = threadIdx.x & 63;
    const int d4   = lane * 4;                 // D == 256
    const int NW   = gridDim.x * 4;            // waves per batch-pair (32)
    const int gw   = blockIdx.x * 4 + widx;
    const int NT   = T - 1;
    const int lo   = 1 + (NT * gw) / NW;
    const int hi   = 1 + (NT * (gw + 1)) / NW;

    // ---- per-d constants ----
    const f4 muv = *(const f4*)(mu + d4);
    const f4 lkv = *(const f4*)(lk + d4);
    const f4 lsv = *(const f4*)(ls + d4);
    float mur[4], kap[4], sv[4];               // sv = sigma^2 / (2 kappa)
    #pragma unroll
    for (int j = 0; j < 4; ++j) {
        mur[j] = muv[j];
        float xk = lkv[j];
        float kappa = fmaxf(xk, 0.0f) + log1pf(__expf(-fabsf(xk))) + 1e-6f;
        float xs = lsv[j];
        float sg = fmaxf(xs, 0.0f) + log1pf(__expf(-fabsf(xs))) + 1e-6f;
        kap[j] = kappa;
        sv[j]  = (sg * sg) * (0.5f / kappa);
    }

    // ---- boundary row t = lo-1 ----
    const size_t yb0 = (size_t)b0 * T * D;
    const size_t yb1 = (size_t)b1 * T * D;
    float tsp[4], yc0[4], yc1[4];
    {
        const f4 t0 = *(const f4*)(ts + (size_t)(lo - 1) * D + d4);
        const f4 a0 = __builtin_nontemporal_load((const f4*)(y + yb0 + (size_t)(lo - 1) * D + d4));
        const f4 a1 = __builtin_nontemporal_load((const f4*)(y + yb1 + (size_t)(lo - 1) * D + d4));
        #pragma unroll
        for (int j = 0; j < 4; ++j) {
            tsp[j] = t0[j];
            yc0[j] = a0[j] - mur[j];
            yc1[j] = a1[j] - mur[j];
        }
    }

    float aq0[4] = {0,0,0,0};   // quadratic terms, batch 0
    float aq1[4] = {0,0,0,0};   // quadratic terms, batch 1
    float al[4]  = {0,0,0,0};   // log-det terms (shared by both batches)

    // ---- lp0 (global wave 0 owns row 0) ----
    if (gw == 0) {
        #pragma unroll
        for (int j = 0; j < 4; ++j) {
            float var0 = fmaxf(sv[j], 1e-10f);
            float iv   = __fdividef(1.0f, var0);
            al[j]  += __logf(var0) + LOG2PI;
            aq0[j] += yc0[j] * yc0[j] * iv;
            aq1[j] += yc1[j] * yc1[j] * iv;
        }
    }

    // ---- main loop, depth-1 software pipeline on 3 streams ----
    const float* tp  = ts + (size_t)lo * D + d4;
    const float* y0p = y + yb0 + (size_t)lo * D + d4;
    const float* y1p = y + yb1 + (size_t)lo * D + d4;

    f4 tc = *(const f4*)tp;
    f4 c0 = __builtin_nontemporal_load((const f4*)y0p);
    f4 c1 = __builtin_nontemporal_load((const f4*)y1p);

    for (int t = lo; t < hi; ++t) {
        f4 tn, n0, n1;
        if (t + 1 < hi) {
            tn = *(const f4*)(tp + D);
            n0 = __builtin_nontemporal_load((const f4*)(y0p + D));
            n1 = __builtin_nontemporal_load((const f4*)(y1p + D));
        }
        tp += D; y0p += D; y1p += D;

        #pragma unroll
        for (int j = 0; j < 4; ++j) {
            float dt = fmaxf(tc[j] - tsp[j], 1e-6f);
            tsp[j]   = tc[j];
            float e  = __expf(-kap[j] * dt);
            float q  = fmaxf(sv[j] * (1.0f - e * e), 1e-10f);
            float iq = __fdividef(1.0f, q);
            al[j]   += __logf(q) + LOG2PI;

            float a = c0[j] - mur[j];
            float r = fmaf(-e, yc0[j], a);
            aq0[j]  = fmaf(r * r, iq, aq0[j]);
            yc0[j]  = a;

            float bb = c1[j] - mur[j];
            float r1 = fmaf(-e, yc1[j], bb);
            aq1[j]   = fmaf(r1 * r1, iq, aq1[j]);
            yc1[j]   = bb;
        }
        tc = tn; c0 = n0; c1 = n1;
    }

    // ---- reduce three sums: lane -> wave -> block -> atomic ----
    float s0 = (aq0[0] + aq0[1]) + (aq0[2] + aq0[3]);
    float s1 = (aq1[0] + aq1[1]) + (aq1[2] + aq1[3]);
    float sl = (al[0]  + al[1])  + (al[2]  + al[3]);
    #pragma unroll
    for (int off = 32; off > 0; off >>= 1) {
        s0 += __shfl_down(s0, off);
        s1 += __shfl_down(s1, off);
        sl += __shfl_down(sl, off);
    }

    __shared__ float w0[4], w1[4], wl[4];
    if (lane == 0) { w0[widx] = s0; w1[widx] = s1; wl[widx] = sl; }
    __syncthreads();
    if (threadIdx.x == 0) {
        float A0 = (w0[0] + w0[1]) + (w0[2] + w0[3]);
        float A1 = (w1[0] + w1[1]) + (w1[2] + w1[3]);
        float AL = (wl[0] + wl[1]) + (wl[2] + wl[3]);
        atomicAdd(out + b0, -0.5f * (A0 + AL));
        atomicAdd(out + b1, -0.5f * (A1 + AL));
    }
}

extern "C" void kernel_launch(void* const* d_in, const int* in_sizes, int n_in,
                              void* d_out, int out_size, void* d_ws, size_t ws_size,
                              hipStream_t stream) {
    const float* y  = (const float*)d_in[0];
    const float* ts = (const float*)d_in[1];
    const float* mu = (const float*)d_in[2];
    const float* lk = (const float*)d_in[3];
    const float* ls = (const float*)d_in[4];
    float* out = (float*)d_out;

    const int D = in_sizes[2];               // 256
    const int T = in_sizes[1] / D;           // 1024
    const int B = in_sizes[0] / (T * D);     // 256

    hipMemsetAsync(d_out, 0, (size_t)out_size * sizeof(float), stream);

    dim3 grid(8, B / 2);
    ou_fused_kernel<<<grid, dim3(256), 0, stream>>>(y, ts, mu, lk, ls, out, B, T, D);
}

// Round 4
// 343.188 us; speedup vs baseline: 1.1669x; 1.0154x over previous
//
#include <hip/hip_runtime.h>

#define LOG2PI 1.8378770664093453f

typedef float f4 __attribute__((ext_vector_type(4)));

// ---------------------------------------------------------------------------
// Fused OU log-prob, 4 batches per block. B=256, T=1024, D=256.
// Grid (8 t-chunks, B/4=64) = 512 blocks = exactly 2 blocks/CU;
// __launch_bounds__(256,2) -> 256-VGPR cap, no spill risk, 8 waves/CU.
// Each wave owns ~32 consecutive transitions for FOUR batches:
//   - ts row loaded once (L2-resident); dt/exp/q/log q computed once per quad
//   - y rows for 4 batches streamed non-temporally (each read exactly once)
//   - LOG2PI added analytically in the epilogue (term-count * LOG2PI)
// y_prev/ts_prev carried in registers; depth-1 load pipeline on 5 streams.
// ---------------------------------------------------------------------------
__global__ __launch_bounds__(256, 2) void ou_fused4_kernel(
    const float* __restrict__ y,    // B*T*D
    const float* __restrict__ ts,   // T*D
    const float* __restrict__ mu,   // D
    const float* __restrict__ lk,   // D
    const float* __restrict__ ls,   // D
    float* __restrict__ out,        // B
    int B, int T, int D)
{
    const int bq   = blockIdx.y * 4;           // first batch of this quad
    const int widx = threadIdx.x >> 6;
    const int lane = threadIdx.x & 63;
    const int d4   = lane * 4;                 // D == 256 == 64 lanes * 4
    const int NW   = gridDim.x * 4;            // waves per batch-quad (32)
    const int gw   = blockIdx.x * 4 + widx;
    const int NT   = T - 1;
    const int lo   = 1 + (NT * gw) / NW;
    const int hi   = 1 + (NT * (gw + 1)) / NW;

    // ---- per-d constants ----
    const f4 muv = *(const f4*)(mu + d4);
    const f4 lkv = *(const f4*)(lk + d4);
    const f4 lsv = *(const f4*)(ls + d4);
    float mur[4], kap[4], sv[4];               // sv = sigma^2 / (2 kappa)
    #pragma unroll
    for (int j = 0; j < 4; ++j) {
        mur[j] = muv[j];
        float xk = lkv[j];
        float kappa = fmaxf(xk, 0.0f) + log1pf(__expf(-fabsf(xk))) + 1e-6f;
        float xs = lsv[j];
        float sg = fmaxf(xs, 0.0f) + log1pf(__expf(-fabsf(xs))) + 1e-6f;
        kap[j] = kappa;
        sv[j]  = (sg * sg) * (0.5f / kappa);
    }

    // ---- boundary row t = lo-1 ----
    const float* yp[4];
    float tsp[4], yc[4][4];
    {
        const f4 t0 = *(const f4*)(ts + (size_t)(lo - 1) * D + d4);
        #pragma unroll
        for (int j = 0; j < 4; ++j) tsp[j] = t0[j];
        #pragma unroll
        for (int bb = 0; bb < 4; ++bb) {
            const size_t yb = (size_t)(bq + bb) * T * D;
            const f4 a = __builtin_nontemporal_load(
                (const f4*)(y + yb + (size_t)(lo - 1) * D + d4));
            #pragma unroll
            for (int j = 0; j < 4; ++j) yc[bb][j] = a[j] - mur[j];
            yp[bb] = y + yb + (size_t)lo * D + d4;
        }
    }

    float aq[4][4];                            // quadratic accum per batch
    #pragma unroll
    for (int bb = 0; bb < 4; ++bb)
        #pragma unroll
        for (int j = 0; j < 4; ++j) aq[bb][j] = 0.0f;
    float al[4] = {0, 0, 0, 0};                // log-det accum (shared)

    // ---- lp0 (global wave 0 owns row 0) ----
    if (gw == 0) {
        #pragma unroll
        for (int j = 0; j < 4; ++j) {
            float var0 = fmaxf(sv[j], 1e-10f);
            float iv   = __fdividef(1.0f, var0);
            al[j]     += __logf(var0);
            #pragma unroll
            for (int bb = 0; bb < 4; ++bb)
                aq[bb][j] += yc[bb][j] * yc[bb][j] * iv;
        }
    }

    // ---- main loop: depth-1 software pipeline on 5 streams ----
    const float* tp = ts + (size_t)lo * D + d4;
    f4 tc = *(const f4*)tp;
    f4 c0 = __builtin_nontemporal_load((const f4*)yp[0]);
    f4 c1 = __builtin_nontemporal_load((const f4*)yp[1]);
    f4 c2 = __builtin_nontemporal_load((const f4*)yp[2]);
    f4 c3 = __builtin_nontemporal_load((const f4*)yp[3]);

    for (int t = lo; t < hi; ++t) {
        f4 tn, n0, n1, n2, n3;
        if (t + 1 < hi) {
            tn = *(const f4*)(tp + D);
            n0 = __builtin_nontemporal_load((const f4*)(yp[0] + D));
            n1 = __builtin_nontemporal_load((const f4*)(yp[1] + D));
            n2 = __builtin_nontemporal_load((const f4*)(yp[2] + D));
            n3 = __builtin_nontemporal_load((const f4*)(yp[3] + D));
        }
        tp += D; yp[0] += D; yp[1] += D; yp[2] += D; yp[3] += D;

        #pragma unroll
        for (int j = 0; j < 4; ++j) {
            float dt = fmaxf(tc[j] - tsp[j], 1e-6f);
            tsp[j]   = tc[j];
            float e  = __expf(-kap[j] * dt);
            float q  = fmaxf(sv[j] * (1.0f - e * e), 1e-10f);
            float iq = __fdividef(1.0f, q);
            al[j]   += __logf(q);

            float a0 = c0[j] - mur[j];
            float r0 = fmaf(-e, yc[0][j], a0);
            aq[0][j] = fmaf(r0 * r0, iq, aq[0][j]);
            yc[0][j] = a0;

            float a1 = c1[j] - mur[j];
            float r1 = fmaf(-e, yc[1][j], a1);
            aq[1][j] = fmaf(r1 * r1, iq, aq[1][j]);
            yc[1][j] = a1;

            float a2 = c2[j] - mur[j];
            float r2 = fmaf(-e, yc[2][j], a2);
            aq[2][j] = fmaf(r2 * r2, iq, aq[2][j]);
            yc[2][j] = a2;

            float a3 = c3[j] - mur[j];
            float r3 = fmaf(-e, yc[3][j], a3);
            aq[3][j] = fmaf(r3 * r3, iq, aq[3][j]);
            yc[3][j] = a3;
        }
        tc = tn; c0 = n0; c1 = n1; c2 = n2; c3 = n3;
    }

    // ---- reduce: 4 quad sums + 1 logdet sum ----
    float s0 = (aq[0][0] + aq[0][1]) + (aq[0][2] + aq[0][3]);
    float s1 = (aq[1][0] + aq[1][1]) + (aq[1][2] + aq[1][3]);
    float s2 = (aq[2][0] + aq[2][1]) + (aq[2][2] + aq[2][3]);
    float s3 = (aq[3][0] + aq[3][1]) + (aq[3][2] + aq[3][3]);
    float sl = (al[0] + al[1]) + (al[2] + al[3]);
    #pragma unroll
    for (int off = 32; off > 0; off >>= 1) {
        s0 += __shfl_down(s0, off);
        s1 += __shfl_down(s1, off);
        s2 += __shfl_down(s2, off);
        s3 += __shfl_down(s3, off);
        sl += __shfl_down(sl, off);
    }

    __shared__ float w[5][4];
    if (lane == 0) {
        w[0][widx] = s0; w[1][widx] = s1; w[2][widx] = s2;
        w[3][widx] = s3; w[4][widx] = sl;
    }
    __syncthreads();
    if (threadIdx.x == 0) {
        float A0 = (w[0][0] + w[0][1]) + (w[0][2] + w[0][3]);
        float A1 = (w[1][0] + w[1][1]) + (w[1][2] + w[1][3]);
        float A2 = (w[2][0] + w[2][1]) + (w[2][2] + w[2][3]);
        float A3 = (w[3][0] + w[3][1]) + (w[3][2] + w[3][3]);
        float AL = (w[4][0] + w[4][1]) + (w[4][2] + w[4][3]);
        // analytic LOG2PI: this block covered t in [lo_b, hi_b) plus
        // (block 0 only) the D lp0 terms.
        const int lo_b = 1 + (NT * (blockIdx.x * 4)) / NW;
        const int hi_b = 1 + (NT * (blockIdx.x * 4 + 4)) / NW;
        int terms = (hi_b - lo_b) * D + (blockIdx.x == 0 ? D : 0);
        AL += LOG2PI * (float)terms;
        atomicAdd(out + bq + 0, -0.5f * (A0 + AL));
        atomicAdd(out + bq + 1, -0.5f * (A1 + AL));
        atomicAdd(out + bq + 2, -0.5f * (A2 + AL));
        atomicAdd(out + bq + 3, -0.5f * (A3 + AL));
    }
}

extern "C" void kernel_launch(void* const* d_in, const int* in_sizes, int n_in,
                              void* d_out, int out_size, void* d_ws, size_t ws_size,
                              hipStream_t stream) {
    const float* y  = (const float*)d_in[0];
    const float* ts = (const float*)d_in[1];
    const float* mu = (const float*)d_in[2];
    const float* lk = (const float*)d_in[3];
    const float* ls = (const float*)d_in[4];
    float* out = (float*)d_out;

    const int D = in_sizes[2];               // 256
    const int T = in_sizes[1] / D;           // 1024
    const int B = in_sizes[0] / (T * D);     // 256

    hipMemsetAsync(d_out, 0, (size_t)out_size * sizeof(float), stream);

    dim3 grid(8, B / 4);
    ou_fused4_kernel<<<grid, dim3(256), 0, stream>>>(y, ts, mu, lk, ls, out, B, T, D);
}